// Round 4
// baseline (833.306 us; speedup 1.0000x reference)
//
#include <hip/hip_runtime.h>

#define BB 256
#define TT 512
#define II 64
#define DD 512
#define OO 128
#define LN_EPS 1e-5f

__device__ __forceinline__ float fast_tanh(float x) {
    // tanh(x) = 1 - 2/(exp(2x)+1); exact saturation at +/-inf
    float e = __expf(2.0f * x);
    return 1.0f - 2.0f / (e + 1.0f);
}

__global__ __launch_bounds__(512, 2)
void fpm_kernel(const float* __restrict__ x,
                const float* __restrict__ W_in,
                const float* __restrict__ b_in,
                const float* __restrict__ gamma,
                const float* __restrict__ beta,
                const float* __restrict__ W_out,
                const float* __restrict__ b_out,
                const float* __restrict__ cs,
                float* __restrict__ out)
{
    const int b    = blockIdx.x;      // batch row
    const int tid  = threadIdx.x;     // 0..511 == d
    const int wave = tid >> 6;
    const int lane = tid & 63;

    __shared__ float red[2][8][2];    // [parity][wave][{sum, sumsq}]
    __shared__ float h_lds[DD];

    // Stage W_in row d into 64 VGPRs. Rounds 1/3 showed the compiler demotes
    // these to per-step L2 reloads (VGPR_Count 48/56, ~17GB L2 traffic,
    // 600-790us). The in-LOOP asm pin below makes reload illegal: each
    // iteration's w[i] is the previous iteration's asm output, an opaque
    // loop-carried register value the compiler cannot rematerialize from
    // memory.
    float w[II];
    const float4* Wrow = (const float4*)(W_in + tid * II);
    #pragma unroll
    for (int q = 0; q < II / 4; ++q) {
        float4 v = Wrow[q];
        w[4*q+0] = v.x; w[4*q+1] = v.y; w[4*q+2] = v.z; w[4*q+3] = v.w;
    }

    const float bi = b_in[tid];
    const float g  = gamma[tid];
    const float bt = beta[tid];
    const float scale = 1.0f / (1.0f + __expf(-cs[0]));

    const float* xrow = x + (size_t)b * TT * II;

    float s_prev = 0.0f, h_prev = 0.0f;

    // prologue: matvec for t = 0
    float a;
    {
        const float* xt = xrow;
        float a0 = 0.f, a1 = 0.f, a2 = 0.f, a3 = 0.f;
        #pragma unroll
        for (int i = 0; i < II; i += 4) {
            a0 = fmaf(xt[i+0], w[i+0], a0);
            a1 = fmaf(xt[i+1], w[i+1], a1);
            a2 = fmaf(xt[i+2], w[i+2], a2);
            a3 = fmaf(xt[i+3], w[i+3], a3);
        }
        a = (a0 + a1) + (a2 + a3);
    }

    #pragma unroll 1
    for (int t = 0; t < TT; ++t) {
        // --- the pin: redefine w[] in registers every iteration (0 instrs) ---
        #pragma unroll
        for (int i = 0; i < II; ++i) {
            asm("" : "+v"(w[i]));
        }

        float e = fast_tanh(a + bi);
        float s = fast_tanh(e + scale * s_prev + h_prev);

        // --- wave reduction: shfl_xor butterfly (proven correct) ---
        float r0 = s, r1 = s * s;
        #pragma unroll
        for (int m = 32; m >= 1; m >>= 1) {
            r0 += __shfl_xor(r0, m, 64);
            r1 += __shfl_xor(r1, m, 64);
        }
        const int p = t & 1;
        if (lane == 0) { red[p][wave][0] = r0; red[p][wave][1] = r1; }
        __syncthreads();

        // issue cross-wave partial reads, then hide their latency under the
        // matvec for step t+1 (independent of step t's LN)
        float pr[16];
        #pragma unroll
        for (int wv = 0; wv < 8; ++wv) {
            pr[2*wv+0] = red[p][wv][0];
            pr[2*wv+1] = red[p][wv][1];
        }

        {
            const float* xt = xrow + ((t + 1) & (TT - 1)) * II; // t=511 wraps (result unused)
            float a0 = 0.f, a1 = 0.f, a2 = 0.f, a3 = 0.f;
            #pragma unroll
            for (int i = 0; i < II; i += 4) {
                a0 = fmaf(xt[i+0], w[i+0], a0);
                a1 = fmaf(xt[i+1], w[i+1], a1);
                a2 = fmaf(xt[i+2], w[i+2], a2);
                a3 = fmaf(xt[i+3], w[i+3], a3);
            }
            a = (a0 + a1) + (a2 + a3);
        }

        float sum   = ((pr[0] + pr[2]) + (pr[4] + pr[6])) + ((pr[8] + pr[10]) + (pr[12] + pr[14]));
        float sumsq = ((pr[1] + pr[3]) + (pr[5] + pr[7])) + ((pr[9] + pr[11]) + (pr[13] + pr[15]));

        const float mu   = sum * (1.0f / DD);
        const float var  = sumsq * (1.0f / DD) - mu * mu;
        const float rstd = rsqrtf(var + LN_EPS);
        const float h    = (s - mu) * rstd * g + bt;

        s_prev = s;
        h_prev = h;
    }

    // --- output GEMM: logits[b, o] = h . W_out[o, :] + b_out[o] ---
    h_lds[tid] = h_prev;
    __syncthreads();

    const int dbase = lane * 8;
    float hreg[8];
    #pragma unroll
    for (int k = 0; k < 8; ++k) hreg[k] = h_lds[dbase + k];

    for (int oo = 0; oo < 16; ++oo) {
        const int o = wave * 16 + oo;
        const float* wo = W_out + (size_t)o * DD + dbase;  // wave reads 2KB contiguous
        float pacc = 0.f;
        #pragma unroll
        for (int k = 0; k < 8; ++k) pacc = fmaf(wo[k], hreg[k], pacc);
        #pragma unroll
        for (int m = 32; m >= 1; m >>= 1) pacc += __shfl_xor(pacc, m, 64);
        if (lane == 0) out[(size_t)b * OO + o] = pacc + b_out[o];
    }
}

extern "C" void kernel_launch(void* const* d_in, const int* in_sizes, int n_in,
                              void* d_out, int out_size, void* d_ws, size_t ws_size,
                              hipStream_t stream) {
    const float* x      = (const float*)d_in[0];
    const float* W_in   = (const float*)d_in[1];
    const float* b_in   = (const float*)d_in[2];
    const float* gamma  = (const float*)d_in[3];
    const float* beta   = (const float*)d_in[4];
    const float* W_out  = (const float*)d_in[5];
    const float* b_out  = (const float*)d_in[6];
    const float* cs     = (const float*)d_in[7];
    float* out = (float*)d_out;

    fpm_kernel<<<BB, 512, 0, stream>>>(x, W_in, b_in, gamma, beta, W_out, b_out, cs, out);
}

// Round 5
// 826.283 us; speedup vs baseline: 1.0085x; 1.0085x over previous
//
#include <hip/hip_runtime.h>

#define BB 256
#define TT 512
#define II 64
#define DD 512
#define OO 128
#define LN_EPS 1e-5f

__device__ __forceinline__ float fast_tanh(float x) {
    // tanh(x) = 1 - 2/(exp(2x)+1); exact saturation at +/-inf
    float e = __expf(2.0f * x);
    return 1.0f - 2.0f / (e + 1.0f);
}

__global__ __launch_bounds__(512, 2)
void fpm_kernel(const float* __restrict__ x,
                const float* __restrict__ W_in,
                const float* __restrict__ b_in,
                const float* __restrict__ gamma,
                const float* __restrict__ beta,
                const float* __restrict__ W_out,
                const float* __restrict__ b_out,
                const float* __restrict__ cs,
                float* __restrict__ out)
{
    const int b    = blockIdx.x;      // batch row
    const int tid  = threadIdx.x;     // 0..511 == d
    const int wave = tid >> 6;
    const int lane = tid & 63;

    __shared__ float red[2][8][2];    // [parity][wave][{sum, sumsq}]
    __shared__ float h_lds[DD];

    // Stage W_in row d into 64 VGPRs. Rounds 1/3/4 showed the compiler
    // demotes these to per-step L2 reloads (VGPR_Count 48-56, ~17GB L2
    // traffic, 600-830us). Rounds 3/4's pins were NON-volatile asm with
    // outputs -> LLVM may treat them as pure and delete them (it did).
    // VOLATILE asm cannot be deleted/CSE'd/hoisted: each iteration's w[i]
    // is the previous iteration's opaque asm output, so reloading from
    // W_in would be a miscompile. Zero instructions emitted.
    float w[II];
    const float4* Wrow = (const float4*)(W_in + tid * II);
    #pragma unroll
    for (int q = 0; q < II / 4; ++q) {
        float4 v = Wrow[q];
        w[4*q+0] = v.x; w[4*q+1] = v.y; w[4*q+2] = v.z; w[4*q+3] = v.w;
    }

    const float bi = b_in[tid];
    const float g  = gamma[tid];
    const float bt = beta[tid];
    const float scale = 1.0f / (1.0f + __expf(-cs[0]));

    const float* xrow = x + (size_t)b * TT * II;

    float s_prev = 0.0f, h_prev = 0.0f;

    // prologue: matvec for t = 0
    float a;
    {
        const float* xt = xrow;
        float a0 = 0.f, a1 = 0.f, a2 = 0.f, a3 = 0.f;
        #pragma unroll
        for (int i = 0; i < II; i += 4) {
            a0 = fmaf(xt[i+0], w[i+0], a0);
            a1 = fmaf(xt[i+1], w[i+1], a1);
            a2 = fmaf(xt[i+2], w[i+2], a2);
            a3 = fmaf(xt[i+3], w[i+3], a3);
        }
        a = (a0 + a1) + (a2 + a3);
    }

    #pragma unroll 1
    for (int t = 0; t < TT; ++t) {
        // --- the pin: volatile, in-loop, zero-instruction ---
        #pragma unroll
        for (int i = 0; i < II; ++i) {
            asm volatile("" : "+v"(w[i]));
        }

        float e = fast_tanh(a + bi);
        float s = fast_tanh(e + scale * s_prev + h_prev);

        // --- wave reduction: shfl_xor butterfly (proven correct) ---
        float r0 = s, r1 = s * s;
        #pragma unroll
        for (int m = 32; m >= 1; m >>= 1) {
            r0 += __shfl_xor(r0, m, 64);
            r1 += __shfl_xor(r1, m, 64);
        }
        const int p = t & 1;
        if (lane == 0) { red[p][wave][0] = r0; red[p][wave][1] = r1; }
        __syncthreads();

        // issue cross-wave partial reads, then hide their latency under the
        // matvec for step t+1 (independent of step t's LN)
        float pr[16];
        #pragma unroll
        for (int wv = 0; wv < 8; ++wv) {
            pr[2*wv+0] = red[p][wv][0];
            pr[2*wv+1] = red[p][wv][1];
        }

        {
            const float* xt = xrow + ((t + 1) & (TT - 1)) * II; // t=511 wraps (result unused)
            float a0 = 0.f, a1 = 0.f, a2 = 0.f, a3 = 0.f;
            #pragma unroll
            for (int i = 0; i < II; i += 4) {
                a0 = fmaf(xt[i+0], w[i+0], a0);
                a1 = fmaf(xt[i+1], w[i+1], a1);
                a2 = fmaf(xt[i+2], w[i+2], a2);
                a3 = fmaf(xt[i+3], w[i+3], a3);
            }
            a = (a0 + a1) + (a2 + a3);
        }

        float sum   = ((pr[0] + pr[2]) + (pr[4] + pr[6])) + ((pr[8] + pr[10]) + (pr[12] + pr[14]));
        float sumsq = ((pr[1] + pr[3]) + (pr[5] + pr[7])) + ((pr[9] + pr[11]) + (pr[13] + pr[15]));

        const float mu   = sum * (1.0f / DD);
        const float var  = sumsq * (1.0f / DD) - mu * mu;
        const float rstd = rsqrtf(var + LN_EPS);
        const float h    = (s - mu) * rstd * g + bt;

        s_prev = s;
        h_prev = h;
    }

    // --- output GEMM: logits[b, o] = h . W_out[o, :] + b_out[o] ---
    h_lds[tid] = h_prev;
    __syncthreads();

    const int dbase = lane * 8;
    float hreg[8];
    #pragma unroll
    for (int k = 0; k < 8; ++k) hreg[k] = h_lds[dbase + k];

    for (int oo = 0; oo < 16; ++oo) {
        const int o = wave * 16 + oo;
        const float* wo = W_out + (size_t)o * DD + dbase;  // wave reads 2KB contiguous
        float pacc = 0.f;
        #pragma unroll
        for (int k = 0; k < 8; ++k) pacc = fmaf(wo[k], hreg[k], pacc);
        #pragma unroll
        for (int m = 32; m >= 1; m >>= 1) pacc += __shfl_xor(pacc, m, 64);
        if (lane == 0) out[(size_t)b * OO + o] = pacc + b_out[o];
    }
}

extern "C" void kernel_launch(void* const* d_in, const int* in_sizes, int n_in,
                              void* d_out, int out_size, void* d_ws, size_t ws_size,
                              hipStream_t stream) {
    const float* x      = (const float*)d_in[0];
    const float* W_in   = (const float*)d_in[1];
    const float* b_in   = (const float*)d_in[2];
    const float* gamma  = (const float*)d_in[3];
    const float* beta   = (const float*)d_in[4];
    const float* W_out  = (const float*)d_in[5];
    const float* b_out  = (const float*)d_in[6];
    const float* cs     = (const float*)d_in[7];
    float* out = (float*)d_out;

    fpm_kernel<<<BB, 512, 0, stream>>>(x, W_in, b_in, gamma, beta, W_out, b_out, cs, out);
}

// Round 6
// 506.076 us; speedup vs baseline: 1.6466x; 1.6327x over previous
//
#include <hip/hip_runtime.h>

#define BB 256
#define TT 512
#define II 64
#define DD 512
#define OO 128
#define LN_EPS 1e-5f
#define XS_STRIDE 68   // 64 + 4 pad: rows 16B-aligned; inner reads are
                       // wave-uniform in i so any aligned stride is conflict-free

__device__ __forceinline__ float fast_tanh(float x) {
    // tanh(x) = 1 - 2/(exp(2x)+1); exact saturation at +/-inf
    float e = __expf(2.0f * x);
    return 1.0f - 2.0f / (e + 1.0f);
}

// ---------------------------------------------------------------------------
// Kernel 1: E[b][tau][d] = tanh(X[b, t0+tau, :] . W_in[d, :] + b_in[d])
// 64n x 64d tile per 256-thread block; 4x4 outputs/thread; operands in LDS
// transposed [i][n] so the inner loop is 2x ds_read_b128 + 16 v_fma per i.
// No large per-thread arrays -> nothing for the compiler to demote.
// ---------------------------------------------------------------------------
__global__ __launch_bounds__(256, 4)
void embed_kernel(const float* __restrict__ x,
                  const float* __restrict__ W_in,
                  const float* __restrict__ b_in,
                  float* __restrict__ E,
                  int t0, int CT)
{
    __shared__ float xs[II][XS_STRIDE];  // [i][n]
    __shared__ float ws[II][XS_STRIDE];  // [i][d]

    const int tiles_per_b = CT >> 6;
    const int bx   = blockIdx.x;
    const int b    = bx / tiles_per_b;
    const int tau0 = (bx - b * tiles_per_b) << 6;   // chunk-local time base
    const int d0   = blockIdx.y << 6;
    const int tid  = threadIdx.x;

    // stage both 64x64 tiles (coalesced float4 global reads, transposed LDS writes)
    {
        const int r0 = tid >> 4;       // 0..15
        const int c4 = tid & 15;       // float4 column
        #pragma unroll
        for (int rr = 0; rr < 4; ++rr) {
            const int row = r0 + (rr << 4);   // 0..63
            const float4 xv = *(const float4*)(x + ((size_t)(b * TT + t0 + tau0 + row)) * II + c4 * 4);
            const float4 wv = *(const float4*)(W_in + ((size_t)(d0 + row)) * II + c4 * 4);
            xs[c4 * 4 + 0][row] = xv.x; xs[c4 * 4 + 1][row] = xv.y;
            xs[c4 * 4 + 2][row] = xv.z; xs[c4 * 4 + 3][row] = xv.w;
            ws[c4 * 4 + 0][row] = wv.x; ws[c4 * 4 + 1][row] = wv.y;
            ws[c4 * 4 + 2][row] = wv.z; ws[c4 * 4 + 3][row] = wv.w;
        }
    }
    __syncthreads();

    const int tn = tid & 15;   // n-group: rows tn*4..tn*4+3
    const int td = tid >> 4;   // d-group: cols td*4..td*4+3

    float acc[4][4];
    #pragma unroll
    for (int j = 0; j < 4; ++j)
        #pragma unroll
        for (int k = 0; k < 4; ++k) acc[j][k] = 0.0f;

    #pragma unroll 8
    for (int i = 0; i < II; ++i) {
        const float4 xv = *(const float4*)&xs[i][tn * 4];  // 16B-aligned, bcast x4
        const float4 wv = *(const float4*)&ws[i][td * 4];  // 16B-aligned, bcast x16
        acc[0][0] = fmaf(xv.x, wv.x, acc[0][0]);
        acc[0][1] = fmaf(xv.x, wv.y, acc[0][1]);
        acc[0][2] = fmaf(xv.x, wv.z, acc[0][2]);
        acc[0][3] = fmaf(xv.x, wv.w, acc[0][3]);
        acc[1][0] = fmaf(xv.y, wv.x, acc[1][0]);
        acc[1][1] = fmaf(xv.y, wv.y, acc[1][1]);
        acc[1][2] = fmaf(xv.y, wv.z, acc[1][2]);
        acc[1][3] = fmaf(xv.y, wv.w, acc[1][3]);
        acc[2][0] = fmaf(xv.z, wv.x, acc[2][0]);
        acc[2][1] = fmaf(xv.z, wv.y, acc[2][1]);
        acc[2][2] = fmaf(xv.z, wv.z, acc[2][2]);
        acc[2][3] = fmaf(xv.z, wv.w, acc[2][3]);
        acc[3][0] = fmaf(xv.w, wv.x, acc[3][0]);
        acc[3][1] = fmaf(xv.w, wv.y, acc[3][1]);
        acc[3][2] = fmaf(xv.w, wv.z, acc[3][2]);
        acc[3][3] = fmaf(xv.w, wv.w, acc[3][3]);
    }

    const int dg = d0 + td * 4;
    const float4 bv = *(const float4*)(b_in + dg);
    #pragma unroll
    for (int j = 0; j < 4; ++j) {
        const int n = tau0 + tn * 4 + j;   // chunk-local time index
        float4 ev;
        ev.x = fast_tanh(acc[j][0] + bv.x);
        ev.y = fast_tanh(acc[j][1] + bv.y);
        ev.z = fast_tanh(acc[j][2] + bv.z);
        ev.w = fast_tanh(acc[j][3] + bv.w);
        *(float4*)(E + ((size_t)(b * CT + n)) * DD + dg) = ev;
    }
}

// ---------------------------------------------------------------------------
// Kernel 2: per-row recurrence + LN over a chunk of CT steps, reading E.
// One block per batch row, thread = d. e prefetched 2 steps ahead.
// ---------------------------------------------------------------------------
__global__ __launch_bounds__(512, 2)
void recur_kernel(const float* __restrict__ E,
                  const float* __restrict__ gamma,
                  const float* __restrict__ beta,
                  const float* __restrict__ W_out,
                  const float* __restrict__ b_out,
                  const float* __restrict__ cs,
                  float* __restrict__ s_state,
                  float* __restrict__ h_state,
                  float* __restrict__ out,
                  int CT, int is_first, int is_last)
{
    const int b    = blockIdx.x;
    const int tid  = threadIdx.x;
    const int wave = tid >> 6;
    const int lane = tid & 63;

    __shared__ float red[2][8][2];
    __shared__ float h_lds[DD];

    const float g  = gamma[tid];
    const float bt = beta[tid];
    const float scale = 1.0f / (1.0f + __expf(-cs[0]));

    float s_prev, h_prev;
    if (is_first) { s_prev = 0.0f; h_prev = 0.0f; }
    else {
        s_prev = s_state[(size_t)b * DD + tid];
        h_prev = h_state[(size_t)b * DD + tid];
    }

    const float* Eb = E + (size_t)b * CT * DD;
    float e0 = Eb[tid];
    float e1 = Eb[(size_t)DD + tid];   // CT >= 64 always

    #pragma unroll 1
    for (int tau = 0; tau < CT; ++tau) {
        const int tpre = (tau + 2 < CT) ? tau + 2 : CT - 1;
        const float e2 = Eb[(size_t)tpre * DD + tid];   // prefetch (2 ahead)

        const float s = fast_tanh(e0 + scale * s_prev + h_prev);

        // wave butterfly (proven correct)
        float r0 = s, r1 = s * s;
        #pragma unroll
        for (int m = 32; m >= 1; m >>= 1) {
            r0 += __shfl_xor(r0, m, 64);
            r1 += __shfl_xor(r1, m, 64);
        }
        const int p = tau & 1;
        if (lane == 0) { red[p][wave][0] = r0; red[p][wave][1] = r1; }
        __syncthreads();

        float sum = 0.f, sumsq = 0.f;
        #pragma unroll
        for (int wv = 0; wv < 8; ++wv) {
            sum   += red[p][wv][0];
            sumsq += red[p][wv][1];
        }

        const float mu   = sum * (1.0f / DD);
        const float var  = sumsq * (1.0f / DD) - mu * mu;
        const float rstd = rsqrtf(var + LN_EPS);
        const float h    = (s - mu) * rstd * g + bt;

        s_prev = s;
        h_prev = h;
        e0 = e1;
        e1 = e2;
    }

    if (!is_last) {
        s_state[(size_t)b * DD + tid] = s_prev;
        h_state[(size_t)b * DD + tid] = h_prev;
    } else {
        // logits[b, o] = h . W_out[o, :] + b_out[o]
        h_lds[tid] = h_prev;
        __syncthreads();

        const int dbase = lane * 8;
        float hreg[8];
        #pragma unroll
        for (int k = 0; k < 8; ++k) hreg[k] = h_lds[dbase + k];

        for (int oo = 0; oo < 16; ++oo) {
            const int o = wave * 16 + oo;
            const float* wo = W_out + (size_t)o * DD + dbase;
            float pacc = 0.f;
            #pragma unroll
            for (int k = 0; k < 8; ++k) pacc = fmaf(wo[k], hreg[k], pacc);
            #pragma unroll
            for (int m = 32; m >= 1; m >>= 1) pacc += __shfl_xor(pacc, m, 64);
            if (lane == 0) out[(size_t)b * OO + o] = pacc + b_out[o];
        }
    }
}

extern "C" void kernel_launch(void* const* d_in, const int* in_sizes, int n_in,
                              void* d_out, int out_size, void* d_ws, size_t ws_size,
                              hipStream_t stream) {
    const float* x      = (const float*)d_in[0];
    const float* W_in   = (const float*)d_in[1];
    const float* b_in   = (const float*)d_in[2];
    const float* gamma  = (const float*)d_in[3];
    const float* beta   = (const float*)d_in[4];
    const float* W_out  = (const float*)d_in[5];
    const float* b_out  = (const float*)d_in[6];
    const float* cs     = (const float*)d_in[7];
    float* out = (float*)d_out;

    // Workspace: [ E_chunk (BB*CT*DD fp32) | s_state (BB*DD) | h_state (BB*DD) ]
    // Pick the largest chunk CT in {512,256,128,64} that fits ws_size.
    const size_t state_bytes = (size_t)BB * DD * sizeof(float);
    int CT = TT;
    while (CT > 64 &&
           (size_t)BB * CT * DD * sizeof(float) + 2 * state_bytes > ws_size) {
        CT >>= 1;
    }
    float* E       = (float*)d_ws;
    float* s_state = (float*)((char*)d_ws + (size_t)BB * CT * DD * sizeof(float));
    float* h_state = s_state + (size_t)BB * DD;

    const int nchunks = TT / CT;
    for (int c = 0; c < nchunks; ++c) {
        dim3 g1(BB * (CT >> 6), DD >> 6);
        embed_kernel<<<g1, 256, 0, stream>>>(x, W_in, b_in, E, c * CT, CT);
        recur_kernel<<<BB, 512, 0, stream>>>(E, gamma, beta, W_out, b_out, cs,
                                             s_state, h_state, out, CT,
                                             (c == 0) ? 1 : 0,
                                             (c == nchunks - 1) ? 1 : 0);
    }
}